// Round 1
// baseline (280.717 us; speedup 1.0000x reference)
//
#include <hip/hip_runtime.h>

#define T_DIM 2048
#define B_DIM 32
#define F_DIM 1024
#define H_DIM 1024
#define PEN   -99999.0f

// d_out layout (floats): summary [32][1024] @ 0, distribution [2048][32] @ 32768,
// copy_distribution [2048][32] @ 98304.
#define SUM_OFF  0
#define DIST_OFF 32768
#define COPY_OFF 98304

// ws layout (floats)
#define WS_QFULL 0        // [32][2048]
#define WS_V     65536    // [64][1024]  (bc = b*2+c)
#define WS_CB    131072   // [64]
#define WS_FBAR  131328   // [32][1024]
#define WS_VPART 164096   // [8][64][1024]
#define HCHUNKS  8
#define HPERCHUNK (H_DIM / HCHUNKS)   // 128

// out[b*J + j] = dot(W[j,:], X[b,:]) + bias[j].  4 rows per wave.
template<int J>
__global__ void rowproj(const float* __restrict__ W, const float* __restrict__ X,
                        const float* __restrict__ bias, float* __restrict__ out) {
    int wave = (blockIdx.x * blockDim.x + threadIdx.x) >> 6;
    int lane = threadIdx.x & 63;
    int j0 = wave * 4;
    if (j0 >= J) return;
    float4 w[4][4];
    for (int r = 0; r < 4; ++r)
        for (int q = 0; q < 4; ++q)
            w[r][q] = *(const float4*)(W + (size_t)(j0 + r) * F_DIM + q * 256 + lane * 4);
    for (int b = 0; b < B_DIM; ++b) {
        float4 x[4];
        for (int q = 0; q < 4; ++q)
            x[q] = *(const float4*)(X + b * F_DIM + q * 256 + lane * 4);
        float acc[4] = {0.f, 0.f, 0.f, 0.f};
        for (int r = 0; r < 4; ++r)
            for (int q = 0; q < 4; ++q)
                acc[r] += w[r][q].x * x[q].x + w[r][q].y * x[q].y
                        + w[r][q].z * x[q].z + w[r][q].w * x[q].w;
        for (int r = 0; r < 4; ++r) {
            float a = acc[r];
            for (int off = 32; off; off >>= 1) a += __shfl_xor(a, off, 64);
            if (lane == 0) out[b * J + j0 + r] = a + bias[j0 + r];
        }
    }
}

// vpart[chunk][bc][f] = sum_{h in chunk} Wk[h][f] * qfull[b][2h+c]
__global__ void vproj(const float* __restrict__ Wk, const float* __restrict__ qfull,
                      float* __restrict__ vpart) {
    __shared__ float qs[B_DIM][2 * HPERCHUNK];   // 32 KB
    int ftile = blockIdx.x;        // 16 tiles of 64 f
    int chunk = blockIdx.y;        // 8 h-chunks of 128
    int tid = threadIdx.x;
    int f = ftile * 64 + (tid & 63);
    int g = tid >> 6;              // bc group 0..3
    int h0 = chunk * HPERCHUNK;
    for (int idx = tid; idx < B_DIM * 2 * HPERCHUNK; idx += 256) {
        int b = idx / (2 * HPERCHUNK);
        int rem = idx % (2 * HPERCHUNK);
        qs[b][rem] = qfull[b * 2048 + 2 * h0 + rem];
    }
    __syncthreads();
    float acc[16];
    for (int i = 0; i < 16; ++i) acc[i] = 0.f;
    for (int hh = 0; hh < HPERCHUNK; ++hh) {
        float wk = Wk[(size_t)(h0 + hh) * F_DIM + f];
        #pragma unroll
        for (int i = 0; i < 16; ++i) {
            int bc = g * 16 + i;
            acc[i] += wk * qs[bc >> 1][2 * hh + (bc & 1)];
        }
    }
    for (int i = 0; i < 16; ++i) {
        int bc = g * 16 + i;
        vpart[((size_t)chunk * 64 + bc) * F_DIM + f] = acc[i];
    }
}

__global__ void vreduce(const float* __restrict__ vpart, float* __restrict__ v) {
    int idx = blockIdx.x * 256 + threadIdx.x;   // 0..65535
    float s = 0.f;
    for (int c = 0; c < HCHUNKS; ++c) s += vpart[c * 65536 + idx];
    v[idx] = s;
}

__global__ void cbkern(const float* __restrict__ bk, const float* __restrict__ qfull,
                       float* __restrict__ cb) {
    __shared__ float red[256];
    int tid = threadIdx.x;
    int bc = tid & 63, p = tid >> 6;
    int b = bc >> 1, c = bc & 1;
    float s = 0.f;
    for (int h = p; h < H_DIM; h += 4)
        s += bk[h] * qfull[b * 2048 + 2 * h + c];
    red[tid] = s;
    __syncthreads();
    if (p == 0) cb[bc] = red[bc] + red[64 + bc] + red[128 + bc] + red[192 + bc];
}

#define TGROUP 8
__global__ void scores_kern(const float* __restrict__ feat, const float* __restrict__ v,
                            const float* __restrict__ cb, const float* __restrict__ mask,
                            float* __restrict__ out) {
    int wave = (blockIdx.x * blockDim.x + threadIdx.x) >> 6;
    int lane = threadIdx.x & 63;
    int b = wave >> 8;        // 8192 waves: 32 b * 256 tgroups
    int tg = wave & 255;
    float4 v0[4], v1[4];
    for (int q = 0; q < 4; ++q) {
        v0[q] = *(const float4*)(v + (size_t)(b * 2 + 0) * F_DIM + q * 256 + lane * 4);
        v1[q] = *(const float4*)(v + (size_t)(b * 2 + 1) * F_DIM + q * 256 + lane * 4);
    }
    float c0 = cb[b * 2 + 0], c1 = cb[b * 2 + 1];
    for (int tt = 0; tt < TGROUP; ++tt) {
        int t = tg * TGROUP + tt;
        const float* fr = feat + ((size_t)t * B_DIM + b) * F_DIM;
        float a0 = 0.f, a1 = 0.f;
        for (int q = 0; q < 4; ++q) {
            float4 fv = *(const float4*)(fr + q * 256 + lane * 4);
            a0 += fv.x * v0[q].x + fv.y * v0[q].y + fv.z * v0[q].z + fv.w * v0[q].w;
            a1 += fv.x * v1[q].x + fv.y * v1[q].y + fv.z * v1[q].z + fv.w * v1[q].w;
        }
        for (int off = 32; off; off >>= 1) {
            a0 += __shfl_xor(a0, off, 64);
            a1 += __shfl_xor(a1, off, 64);
        }
        if (lane == 0) {
            float mp = mask[t * B_DIM + b] * PEN;
            out[DIST_OFF + t * B_DIM + b] = a0 + c0 + mp;
            out[COPY_OFF + t * B_DIM + b] = a1 + c1 + mp;
        }
    }
}

__global__ void softmax_kern(float* __restrict__ out) {
    int b = blockIdx.x & 31;
    int c = blockIdx.x >> 5;
    float* col = out + (c ? COPY_OFF : DIST_OFF);
    int tid = threadIdx.x;
    float vals[8];
    float m = -1e30f;
    for (int i = 0; i < 8; ++i) {
        vals[i] = col[(tid + i * 256) * B_DIM + b];
        m = fmaxf(m, vals[i]);
    }
    __shared__ float red[256];
    red[tid] = m; __syncthreads();
    for (int s = 128; s; s >>= 1) {
        if (tid < s) red[tid] = fmaxf(red[tid], red[tid + s]);
        __syncthreads();
    }
    m = red[0]; __syncthreads();
    float l = 0.f;
    for (int i = 0; i < 8; ++i) { vals[i] = __expf(vals[i] - m); l += vals[i]; }
    red[tid] = l; __syncthreads();
    for (int s = 128; s; s >>= 1) {
        if (tid < s) red[tid] += red[tid + s];
        __syncthreads();
    }
    float inv = 1.f / red[0];
    for (int i = 0; i < 8; ++i) col[(tid + i * 256) * B_DIM + b] = vals[i] * inv;
}

__global__ void fbar_kern(const float* __restrict__ feat, const float* __restrict__ out,
                          float* __restrict__ fbar) {
    int b = blockIdx.x & 31;
    int chunk = blockIdx.x >> 5;     // 16 chunks of 128 t
    int tid = threadIdx.x;
    int f4 = tid * 4;
    float4 acc = {0.f, 0.f, 0.f, 0.f};
    int t0 = chunk * 128;
    for (int tt = 0; tt < 128; ++tt) {
        int t = t0 + tt;
        float d = out[DIST_OFF + t * B_DIM + b];
        float4 fv = *(const float4*)(feat + ((size_t)t * B_DIM + b) * F_DIM + f4);
        acc.x += d * fv.x; acc.y += d * fv.y; acc.z += d * fv.z; acc.w += d * fv.w;
    }
    atomicAdd(&fbar[b * F_DIM + f4 + 0], acc.x);
    atomicAdd(&fbar[b * F_DIM + f4 + 1], acc.y);
    atomicAdd(&fbar[b * F_DIM + f4 + 2], acc.z);
    atomicAdd(&fbar[b * F_DIM + f4 + 3], acc.w);
}

extern "C" void kernel_launch(void* const* d_in, const int* in_sizes, int n_in,
                              void* d_out, int out_size, void* d_ws, size_t ws_size,
                              hipStream_t stream) {
    const float* feat   = (const float*)d_in[0];
    const float* hidden = (const float*)d_in[1];
    const float* mask   = (const float*)d_in[2];
    const float* Wk     = (const float*)d_in[3];
    const float* bk     = (const float*)d_in[4];
    const float* Wq     = (const float*)d_in[5];
    const float* bq     = (const float*)d_in[6];
    const float* Wm     = (const float*)d_in[7];
    const float* bm     = (const float*)d_in[8];
    float* out = (float*)d_out;
    float* ws  = (float*)d_ws;

    float* qfull = ws + WS_QFULL;
    float* v     = ws + WS_V;
    float* cb    = ws + WS_CB;
    float* fbar  = ws + WS_FBAR;
    float* vpart = ws + WS_VPART;

    hipMemsetAsync(fbar, 0, 32768 * sizeof(float), stream);
    rowproj<2048><<<128, 256, 0, stream>>>(Wq, hidden, bq, qfull);
    vproj<<<dim3(16, 8), 256, 0, stream>>>(Wk, qfull, vpart);
    vreduce<<<256, 256, 0, stream>>>(vpart, v);
    cbkern<<<1, 256, 0, stream>>>(bk, qfull, cb);
    scores_kern<<<2048, 256, 0, stream>>>(feat, v, cb, mask, out);
    softmax_kern<<<64, 256, 0, stream>>>(out);
    fbar_kern<<<512, 256, 0, stream>>>(feat, out, fbar);
    rowproj<1024><<<64, 256, 0, stream>>>(Wm, fbar, bm, out + SUM_OFF);
}

// Round 2
// 270.906 us; speedup vs baseline: 1.0362x; 1.0362x over previous
//
#include <hip/hip_runtime.h>

#define T_DIM 2048
#define B_DIM 32
#define F_DIM 1024
#define H_DIM 1024
#define PEN   -99999.0f

// d_out layout (floats): summary [32][1024] @ 0, distribution [2048][32] @ 32768,
// copy_distribution [2048][32] @ 98304.
#define SUM_OFF  0
#define DIST_OFF 32768
#define COPY_OFF 98304

// ws layout (floats)
#define WS_QFULL 0        // [32][2048]
#define WS_V     65536    // [64][1024]  (bc = b*2+c)
#define WS_CB    131072   // [64]
#define WS_FBAR  131328   // [32][1024]
#define WS_VPART 164096   // [8][64][1024]
#define WS_FBARPART 688128 // [16][32][1024]
#define HCHUNKS  8
#define HPERCHUNK (H_DIM / HCHUNKS)   // 128
#define TCHUNKS  16

// out[b*J + j] = dot(W[j,:], X[b,:]) + bias[j].  4 rows per wave.
template<int J>
__global__ void rowproj(const float* __restrict__ W, const float* __restrict__ X,
                        const float* __restrict__ bias, float* __restrict__ out) {
    int wave = (blockIdx.x * blockDim.x + threadIdx.x) >> 6;
    int lane = threadIdx.x & 63;
    int j0 = wave * 4;
    if (j0 >= J) return;
    float4 w[4][4];
    for (int r = 0; r < 4; ++r)
        for (int q = 0; q < 4; ++q)
            w[r][q] = *(const float4*)(W + (size_t)(j0 + r) * F_DIM + q * 256 + lane * 4);
    for (int b = 0; b < B_DIM; ++b) {
        float4 x[4];
        for (int q = 0; q < 4; ++q)
            x[q] = *(const float4*)(X + b * F_DIM + q * 256 + lane * 4);
        float acc[4] = {0.f, 0.f, 0.f, 0.f};
        for (int r = 0; r < 4; ++r)
            for (int q = 0; q < 4; ++q)
                acc[r] += w[r][q].x * x[q].x + w[r][q].y * x[q].y
                        + w[r][q].z * x[q].z + w[r][q].w * x[q].w;
        for (int r = 0; r < 4; ++r) {
            float a = acc[r];
            for (int off = 32; off; off >>= 1) a += __shfl_xor(a, off, 64);
            if (lane == 0) out[b * J + j0 + r] = a + bias[j0 + r];
        }
    }
}

// vpart[chunk][bc][f] = sum_{h in chunk} Wk[h][f] * qfull[b][2h+c]
__global__ void vproj(const float* __restrict__ Wk, const float* __restrict__ qfull,
                      float* __restrict__ vpart) {
    __shared__ float qs[B_DIM][2 * HPERCHUNK];   // 32 KB
    int ftile = blockIdx.x;        // 16 tiles of 64 f
    int chunk = blockIdx.y;        // 8 h-chunks of 128
    int tid = threadIdx.x;
    int f = ftile * 64 + (tid & 63);
    int g = tid >> 6;              // bc group 0..3
    int h0 = chunk * HPERCHUNK;
    for (int idx = tid; idx < B_DIM * 2 * HPERCHUNK; idx += 256) {
        int b = idx / (2 * HPERCHUNK);
        int rem = idx % (2 * HPERCHUNK);
        qs[b][rem] = qfull[b * 2048 + 2 * h0 + rem];
    }
    __syncthreads();
    float acc[16];
    for (int i = 0; i < 16; ++i) acc[i] = 0.f;
    for (int hh = 0; hh < HPERCHUNK; ++hh) {
        float wk = Wk[(size_t)(h0 + hh) * F_DIM + f];
        #pragma unroll
        for (int i = 0; i < 16; ++i) {
            int bc = g * 16 + i;
            acc[i] += wk * qs[bc >> 1][2 * hh + (bc & 1)];
        }
    }
    for (int i = 0; i < 16; ++i) {
        int bc = g * 16 + i;
        vpart[((size_t)chunk * 64 + bc) * F_DIM + f] = acc[i];
    }
}

__global__ void vreduce(const float* __restrict__ vpart, float* __restrict__ v) {
    int idx = blockIdx.x * 256 + threadIdx.x;   // 0..65535
    float s = 0.f;
    for (int c = 0; c < HCHUNKS; ++c) s += vpart[c * 65536 + idx];
    v[idx] = s;
}

__global__ void cbkern(const float* __restrict__ bk, const float* __restrict__ qfull,
                       float* __restrict__ cb) {
    __shared__ float red[256];
    int tid = threadIdx.x;
    int bc = tid & 63, p = tid >> 6;
    int b = bc >> 1, c = bc & 1;
    float s = 0.f;
    for (int h = p; h < H_DIM; h += 4)
        s += bk[h] * qfull[b * 2048 + 2 * h + c];
    red[tid] = s;
    __syncthreads();
    if (p == 0) cb[bc] = red[bc] + red[64 + bc] + red[128 + bc] + red[192 + bc];
}

#define TGROUP 8
__global__ void scores_kern(const float* __restrict__ feat, const float* __restrict__ v,
                            const float* __restrict__ cb, const float* __restrict__ mask,
                            float* __restrict__ out) {
    int wave = (blockIdx.x * blockDim.x + threadIdx.x) >> 6;
    int lane = threadIdx.x & 63;
    int b = wave >> 8;        // 8192 waves: 32 b * 256 tgroups
    int tg = wave & 255;
    float4 v0[4], v1[4];
    for (int q = 0; q < 4; ++q) {
        v0[q] = *(const float4*)(v + (size_t)(b * 2 + 0) * F_DIM + q * 256 + lane * 4);
        v1[q] = *(const float4*)(v + (size_t)(b * 2 + 1) * F_DIM + q * 256 + lane * 4);
    }
    float c0 = cb[b * 2 + 0], c1 = cb[b * 2 + 1];
    for (int tt = 0; tt < TGROUP; ++tt) {
        int t = tg * TGROUP + tt;
        const float* fr = feat + ((size_t)t * B_DIM + b) * F_DIM;
        float a0 = 0.f, a1 = 0.f;
        for (int q = 0; q < 4; ++q) {
            float4 fv = *(const float4*)(fr + q * 256 + lane * 4);
            a0 += fv.x * v0[q].x + fv.y * v0[q].y + fv.z * v0[q].z + fv.w * v0[q].w;
            a1 += fv.x * v1[q].x + fv.y * v1[q].y + fv.z * v1[q].z + fv.w * v1[q].w;
        }
        for (int off = 32; off; off >>= 1) {
            a0 += __shfl_xor(a0, off, 64);
            a1 += __shfl_xor(a1, off, 64);
        }
        if (lane == 0) {
            float mp = mask[t * B_DIM + b] * PEN;
            out[DIST_OFF + t * B_DIM + b] = a0 + c0 + mp;
            out[COPY_OFF + t * B_DIM + b] = a1 + c1 + mp;
        }
    }
}

__global__ void softmax_kern(float* __restrict__ out) {
    int b = blockIdx.x & 31;
    int c = blockIdx.x >> 5;
    float* col = out + (c ? COPY_OFF : DIST_OFF);
    int tid = threadIdx.x;
    float vals[8];
    float m = -1e30f;
    for (int i = 0; i < 8; ++i) {
        vals[i] = col[(tid + i * 256) * B_DIM + b];
        m = fmaxf(m, vals[i]);
    }
    __shared__ float red[256];
    red[tid] = m; __syncthreads();
    for (int s = 128; s; s >>= 1) {
        if (tid < s) red[tid] = fmaxf(red[tid], red[tid + s]);
        __syncthreads();
    }
    m = red[0]; __syncthreads();
    float l = 0.f;
    for (int i = 0; i < 8; ++i) { vals[i] = __expf(vals[i] - m); l += vals[i]; }
    red[tid] = l; __syncthreads();
    for (int s = 128; s; s >>= 1) {
        if (tid < s) red[tid] += red[tid + s];
        __syncthreads();
    }
    float inv = 1.f / red[0];
    for (int i = 0; i < 8; ++i) col[(tid + i * 256) * B_DIM + b] = vals[i] * inv;
}

// fbar_part[chunk][b][f] = sum_{t in chunk} dist[t][b] * feat[t][b][f]  (no atomics)
__global__ void fbar_part_kern(const float* __restrict__ feat, const float* __restrict__ out,
                               float* __restrict__ fbar_part) {
    int b = blockIdx.x & 31;
    int chunk = blockIdx.x >> 5;     // 16 chunks of 128 t
    int tid = threadIdx.x;
    int f4 = tid * 4;
    float4 acc = {0.f, 0.f, 0.f, 0.f};
    int t0 = chunk * 128;
    for (int tt = 0; tt < 128; ++tt) {
        int t = t0 + tt;
        float d = out[DIST_OFF + t * B_DIM + b];
        float4 fv = *(const float4*)(feat + ((size_t)t * B_DIM + b) * F_DIM + f4);
        acc.x += d * fv.x; acc.y += d * fv.y; acc.z += d * fv.z; acc.w += d * fv.w;
    }
    *(float4*)(fbar_part + ((size_t)chunk * B_DIM + b) * F_DIM + f4) = acc;
}

__global__ void fbar_reduce(const float* __restrict__ fbar_part, float* __restrict__ fbar) {
    int idx = blockIdx.x * 256 + threadIdx.x;   // 0..32767  (b*1024+f)
    float s = 0.f;
    for (int c = 0; c < TCHUNKS; ++c) s += fbar_part[(size_t)c * 32768 + idx];
    fbar[idx] = s;
}

extern "C" void kernel_launch(void* const* d_in, const int* in_sizes, int n_in,
                              void* d_out, int out_size, void* d_ws, size_t ws_size,
                              hipStream_t stream) {
    const float* feat   = (const float*)d_in[0];
    const float* hidden = (const float*)d_in[1];
    const float* mask   = (const float*)d_in[2];
    const float* Wk     = (const float*)d_in[3];
    const float* bk     = (const float*)d_in[4];
    const float* Wq     = (const float*)d_in[5];
    const float* bq     = (const float*)d_in[6];
    const float* Wm     = (const float*)d_in[7];
    const float* bm     = (const float*)d_in[8];
    float* out = (float*)d_out;
    float* ws  = (float*)d_ws;

    float* qfull     = ws + WS_QFULL;
    float* v         = ws + WS_V;
    float* cb        = ws + WS_CB;
    float* fbar      = ws + WS_FBAR;
    float* vpart     = ws + WS_VPART;
    float* fbar_part = ws + WS_FBARPART;

    rowproj<2048><<<128, 256, 0, stream>>>(Wq, hidden, bq, qfull);
    vproj<<<dim3(16, 8), 256, 0, stream>>>(Wk, qfull, vpart);
    vreduce<<<256, 256, 0, stream>>>(vpart, v);
    cbkern<<<1, 256, 0, stream>>>(bk, qfull, cb);
    scores_kern<<<2048, 256, 0, stream>>>(feat, v, cb, mask, out);
    softmax_kern<<<64, 256, 0, stream>>>(out);
    fbar_part_kern<<<512, 256, 0, stream>>>(feat, out, fbar_part);
    fbar_reduce<<<128, 256, 0, stream>>>(fbar_part, fbar);
    rowproj<1024><<<64, 256, 0, stream>>>(Wm, fbar, bm, out + SUM_OFF);
}

// Round 3
// 179.415 us; speedup vs baseline: 1.5646x; 1.5099x over previous
//
#include <hip/hip_runtime.h>

#define T_DIM 2048
#define B_DIM 32
#define F_DIM 1024
#define H_DIM 1024
#define PEN   -99999.0f

// d_out layout (floats): summary [32][1024] @ 0, distribution [2048][32] @ 32768,
// copy_distribution [2048][32] @ 98304.
#define SUM_OFF  0
#define DIST_OFF 32768
#define COPY_OFF 98304

// ws layout (floats)
#define WS_QFULL 0         // [32][2048]
#define WS_V     65536     // [64][1024]  (bc = b*2+c)
#define WS_CB    131072    // [64]
#define WS_GML   131136    // [32][4]  {M0, invL0, M1, invL1}
#define WS_FBAR  131264    // [32][1024]
#define WS_VPART 164032    // [8][64][1024]
#define WS_PML   688320    // [32*32][4]  {m0,l0,m1,l1} per (b,chunk)
#define WS_PFACC 692416    // [32*32][1024]
#define HCHUNKS  8
#define HPERCHUNK (H_DIM / HCHUNKS)   // 128
#define NCHUNK   32        // t-chunks of 64

// out[b*J + j] = dot(W[j,:], X[b,:]) + bias[j].  4 rows per wave.
template<int J>
__global__ void rowproj(const float* __restrict__ W, const float* __restrict__ X,
                        const float* __restrict__ bias, float* __restrict__ out) {
    int wave = (blockIdx.x * blockDim.x + threadIdx.x) >> 6;
    int lane = threadIdx.x & 63;
    int j0 = wave * 4;
    if (j0 >= J) return;
    float4 w[4][4];
    for (int r = 0; r < 4; ++r)
        for (int q = 0; q < 4; ++q)
            w[r][q] = *(const float4*)(W + (size_t)(j0 + r) * F_DIM + q * 256 + lane * 4);
    for (int b = 0; b < B_DIM; ++b) {
        float4 x[4];
        for (int q = 0; q < 4; ++q)
            x[q] = *(const float4*)(X + b * F_DIM + q * 256 + lane * 4);
        float acc[4] = {0.f, 0.f, 0.f, 0.f};
        for (int r = 0; r < 4; ++r)
            for (int q = 0; q < 4; ++q)
                acc[r] += w[r][q].x * x[q].x + w[r][q].y * x[q].y
                        + w[r][q].z * x[q].z + w[r][q].w * x[q].w;
        for (int r = 0; r < 4; ++r) {
            float a = acc[r];
            for (int off = 32; off; off >>= 1) a += __shfl_xor(a, off, 64);
            if (lane == 0) out[b * J + j0 + r] = a + bias[j0 + r];
        }
    }
}

// vpart[chunk][bc][f] = sum_{h in chunk} Wk[h][f] * qfull[b][2h+c]
__global__ void vproj(const float* __restrict__ Wk, const float* __restrict__ qfull,
                      float* __restrict__ vpart) {
    __shared__ float qs[B_DIM][2 * HPERCHUNK];   // 32 KB
    int ftile = blockIdx.x;        // 16 tiles of 64 f
    int chunk = blockIdx.y;        // 8 h-chunks of 128
    int tid = threadIdx.x;
    int f = ftile * 64 + (tid & 63);
    int g = tid >> 6;              // bc group 0..3
    int h0 = chunk * HPERCHUNK;
    for (int idx = tid; idx < B_DIM * 2 * HPERCHUNK; idx += 256) {
        int b = idx / (2 * HPERCHUNK);
        int rem = idx % (2 * HPERCHUNK);
        qs[b][rem] = qfull[b * 2048 + 2 * h0 + rem];
    }
    __syncthreads();
    float acc[16];
    for (int i = 0; i < 16; ++i) acc[i] = 0.f;
    for (int hh = 0; hh < HPERCHUNK; ++hh) {
        float wk = Wk[(size_t)(h0 + hh) * F_DIM + f];
        #pragma unroll
        for (int i = 0; i < 16; ++i) {
            int bc = g * 16 + i;
            acc[i] += wk * qs[bc >> 1][2 * hh + (bc & 1)];
        }
    }
    for (int i = 0; i < 16; ++i) {
        int bc = g * 16 + i;
        vpart[((size_t)chunk * 64 + bc) * F_DIM + f] = acc[i];
    }
}

__global__ void vreduce(const float* __restrict__ vpart, float* __restrict__ v) {
    int idx = blockIdx.x * 256 + threadIdx.x;   // 0..65535
    float s = 0.f;
    for (int c = 0; c < HCHUNKS; ++c) s += vpart[c * 65536 + idx];
    v[idx] = s;
}

// cb[bc] = dot(bk, q[b,:,c])   — 64 blocks, one per bc
__global__ void cbkern2(const float* __restrict__ bk, const float* __restrict__ qfull,
                        float* __restrict__ cb) {
    int bc = blockIdx.x;
    int b = bc >> 1, c = bc & 1;
    int tid = threadIdx.x;
    float s = 0.f;
    for (int h = tid; h < H_DIM; h += 256)
        s += bk[h] * qfull[b * 2048 + 2 * h + c];
    __shared__ float red[256];
    red[tid] = s; __syncthreads();
    for (int st = 128; st; st >>= 1) {
        if (tid < st) red[tid] += red[tid + st];
        __syncthreads();
    }
    if (tid == 0) cb[bc] = red[0];
}

// Single pass over features: raw scores -> d_out; online (m,l) for both cols;
// unnormalized weighted feature sum per (b, t-chunk of 64).
__global__ void fused_pass(const float* __restrict__ feat, const float* __restrict__ v,
                           const float* __restrict__ cb, const float* __restrict__ mask,
                           float* __restrict__ out, float* __restrict__ pml,
                           float* __restrict__ pfacc) {
    int b = blockIdx.x & 31;
    int chunk = blockIdx.x >> 5;       // 0..31
    int w = threadIdx.x >> 6;          // wave 0..3
    int lane = threadIdx.x & 63;

    float4 v0[4], v1[4];
    #pragma unroll
    for (int q = 0; q < 4; ++q) {
        v0[q] = *(const float4*)(v + (size_t)(b * 2 + 0) * F_DIM + q * 256 + lane * 4);
        v1[q] = *(const float4*)(v + (size_t)(b * 2 + 1) * F_DIM + q * 256 + lane * 4);
    }
    float c0 = cb[b * 2 + 0], c1 = cb[b * 2 + 1];

    float facc[16];
    #pragma unroll
    for (int i = 0; i < 16; ++i) facc[i] = 0.f;
    float m0 = -1e30f, l0 = 0.f, m1 = -1e30f, l1 = 0.f;

    int t0 = chunk * 64 + w * 16;
    const float* frow = feat + ((size_t)t0 * B_DIM + b) * F_DIM;
    float4 fcur[4];
    #pragma unroll
    for (int q = 0; q < 4; ++q) fcur[q] = *(const float4*)(frow + q * 256 + lane * 4);

    for (int tt = 0; tt < 16; ++tt) {
        int t = t0 + tt;
        float4 fx[4];
        #pragma unroll
        for (int q = 0; q < 4; ++q) fx[q] = fcur[q];
        if (tt < 15) {
            const float* fn = feat + ((size_t)(t + 1) * B_DIM + b) * F_DIM;
            #pragma unroll
            for (int q = 0; q < 4; ++q) fcur[q] = *(const float4*)(fn + q * 256 + lane * 4);
        }
        float a0 = 0.f, a1 = 0.f;
        #pragma unroll
        for (int q = 0; q < 4; ++q) {
            a0 += fx[q].x * v0[q].x + fx[q].y * v0[q].y + fx[q].z * v0[q].z + fx[q].w * v0[q].w;
            a1 += fx[q].x * v1[q].x + fx[q].y * v1[q].y + fx[q].z * v1[q].z + fx[q].w * v1[q].w;
        }
        for (int off = 32; off; off >>= 1) {
            a0 += __shfl_xor(a0, off, 64);
            a1 += __shfl_xor(a1, off, 64);
        }
        float mp = mask[t * B_DIM + b] * PEN;
        float s0 = a0 + c0 + mp;
        float s1 = a1 + c1 + mp;
        if (lane == 0) {
            out[DIST_OFF + t * B_DIM + b] = s0;
            out[COPY_OFF + t * B_DIM + b] = s1;
        }
        // online softmax, col0 (with weighted feature accumulation)
        if (s0 > m0) {
            float sc = __expf(m0 - s0);
            l0 *= sc;
            #pragma unroll
            for (int i = 0; i < 16; ++i) facc[i] *= sc;
            m0 = s0;
        }
        float e0 = __expf(s0 - m0);
        l0 += e0;
        #pragma unroll
        for (int q = 0; q < 4; ++q) {
            facc[q * 4 + 0] += e0 * fx[q].x;
            facc[q * 4 + 1] += e0 * fx[q].y;
            facc[q * 4 + 2] += e0 * fx[q].z;
            facc[q * 4 + 3] += e0 * fx[q].w;
        }
        // online softmax, col1 (denominator only)
        if (s1 > m1) { l1 *= __expf(m1 - s1); m1 = s1; }
        l1 += __expf(s1 - m1);
    }

    // combine 4 waves -> one chunk partial
    __shared__ float sfacc[4][F_DIM];   // 16 KB
    __shared__ float sml[4][4];
    #pragma unroll
    for (int q = 0; q < 4; ++q) {
        sfacc[w][q * 256 + lane * 4 + 0] = facc[q * 4 + 0];
        sfacc[w][q * 256 + lane * 4 + 1] = facc[q * 4 + 1];
        sfacc[w][q * 256 + lane * 4 + 2] = facc[q * 4 + 2];
        sfacc[w][q * 256 + lane * 4 + 3] = facc[q * 4 + 3];
    }
    if (lane == 0) {
        sml[w][0] = m0; sml[w][1] = l0; sml[w][2] = m1; sml[w][3] = l1;
    }
    __syncthreads();
    int tid = threadIdx.x;
    float M0 = fmaxf(fmaxf(sml[0][0], sml[1][0]), fmaxf(sml[2][0], sml[3][0]));
    float M1 = fmaxf(fmaxf(sml[0][2], sml[1][2]), fmaxf(sml[2][2], sml[3][2]));
    float L0 = 0.f, L1 = 0.f;
    float g[4];
    #pragma unroll
    for (int ww = 0; ww < 4; ++ww) {
        g[ww] = __expf(sml[ww][0] - M0);
        L0 += sml[ww][1] * g[ww];
        L1 += sml[ww][3] * __expf(sml[ww][2] - M1);
    }
    float4 r;
    r.x = g[0] * sfacc[0][tid * 4 + 0] + g[1] * sfacc[1][tid * 4 + 0]
        + g[2] * sfacc[2][tid * 4 + 0] + g[3] * sfacc[3][tid * 4 + 0];
    r.y = g[0] * sfacc[0][tid * 4 + 1] + g[1] * sfacc[1][tid * 4 + 1]
        + g[2] * sfacc[2][tid * 4 + 1] + g[3] * sfacc[3][tid * 4 + 1];
    r.z = g[0] * sfacc[0][tid * 4 + 2] + g[1] * sfacc[1][tid * 4 + 2]
        + g[2] * sfacc[2][tid * 4 + 2] + g[3] * sfacc[3][tid * 4 + 2];
    r.w = g[0] * sfacc[0][tid * 4 + 3] + g[1] * sfacc[1][tid * 4 + 3]
        + g[2] * sfacc[2][tid * 4 + 3] + g[3] * sfacc[3][tid * 4 + 3];
    *(float4*)(pfacc + ((size_t)(b * NCHUNK + chunk)) * F_DIM + tid * 4) = r;
    if (tid == 0) {
        float4 p = {M0, L0, M1, L1};
        *(float4*)(pml + (b * NCHUNK + chunk) * 4) = p;
    }
}

// per b: combine 32 chunk (m,l) -> global {M0, 1/L0, M1, 1/L1}
__global__ void combine_ml(const float* __restrict__ pml, float* __restrict__ gml) {
    int b = blockIdx.x;
    int lane = threadIdx.x;    // 64 threads, lanes 32..63 idle values
    float m0 = -1e30f, l0 = 0.f, m1 = -1e30f, l1 = 0.f;
    if (lane < NCHUNK) {
        float4 p = *(const float4*)(pml + (b * NCHUNK + lane) * 4);
        m0 = p.x; l0 = p.y; m1 = p.z; l1 = p.w;
    }
    float M0 = m0, M1 = m1;
    for (int off = 32; off; off >>= 1) {
        M0 = fmaxf(M0, __shfl_xor(M0, off, 64));
        M1 = fmaxf(M1, __shfl_xor(M1, off, 64));
    }
    float e0 = l0 * __expf(m0 - M0);
    float e1 = l1 * __expf(m1 - M1);
    for (int off = 32; off; off >>= 1) {
        e0 += __shfl_xor(e0, off, 64);
        e1 += __shfl_xor(e1, off, 64);
    }
    if (lane == 0) {
        float4 p = {M0, 1.f / e0, M1, 1.f / e1};
        *(float4*)(gml + b * 4) = p;
    }
}

// normalize stored raw scores in place: exp(s - M) * invL
__global__ void dist_norm(float* __restrict__ out, const float* __restrict__ gml) {
    int idx = blockIdx.x * 256 + threadIdx.x;   // t*32+b, 0..65535
    int b = idx & 31;
    float4 p = *(const float4*)(gml + b * 4);
    out[DIST_OFF + idx] = __expf(out[DIST_OFF + idx] - p.x) * p.y;
    out[COPY_OFF + idx] = __expf(out[COPY_OFF + idx] - p.z) * p.w;
}

// fbar[b][f] = invL0 * sum_c exp(pm0_c - M0) * pfacc[b][c][f]
__global__ void fbar_combine(const float* __restrict__ pfacc, const float* __restrict__ pml,
                             const float* __restrict__ gml, float* __restrict__ fbar) {
    int idx = blockIdx.x * 256 + threadIdx.x;   // 0..32767
    int b = idx >> 10;
    int f = idx & 1023;
    float M0 = gml[b * 4 + 0];
    float invL = gml[b * 4 + 1];
    float s = 0.f;
    for (int c = 0; c < NCHUNK; ++c)
        s += __expf(pml[(b * NCHUNK + c) * 4] - M0) * pfacc[((size_t)(b * NCHUNK + c)) * F_DIM + f];
    fbar[idx] = s * invL;
}

extern "C" void kernel_launch(void* const* d_in, const int* in_sizes, int n_in,
                              void* d_out, int out_size, void* d_ws, size_t ws_size,
                              hipStream_t stream) {
    const float* feat   = (const float*)d_in[0];
    const float* hidden = (const float*)d_in[1];
    const float* mask   = (const float*)d_in[2];
    const float* Wk     = (const float*)d_in[3];
    const float* bk     = (const float*)d_in[4];
    const float* Wq     = (const float*)d_in[5];
    const float* bq     = (const float*)d_in[6];
    const float* Wm     = (const float*)d_in[7];
    const float* bm     = (const float*)d_in[8];
    float* out = (float*)d_out;
    float* ws  = (float*)d_ws;

    float* qfull = ws + WS_QFULL;
    float* v     = ws + WS_V;
    float* cb    = ws + WS_CB;
    float* gml   = ws + WS_GML;
    float* fbar  = ws + WS_FBAR;
    float* vpart = ws + WS_VPART;
    float* pml   = ws + WS_PML;
    float* pfacc = ws + WS_PFACC;

    rowproj<2048><<<128, 256, 0, stream>>>(Wq, hidden, bq, qfull);
    vproj<<<dim3(16, 8), 256, 0, stream>>>(Wk, qfull, vpart);
    vreduce<<<256, 256, 0, stream>>>(vpart, v);
    cbkern2<<<64, 256, 0, stream>>>(bk, qfull, cb);
    fused_pass<<<1024, 256, 0, stream>>>(feat, v, cb, mask, out, pml, pfacc);
    combine_ml<<<32, 64, 0, stream>>>(pml, gml);
    dist_norm<<<256, 256, 0, stream>>>(out, gml);
    fbar_combine<<<128, 256, 0, stream>>>(pfacc, pml, gml, fbar);
    rowproj<1024><<<64, 256, 0, stream>>>(Wm, fbar, bm, out + SUM_OFF);
}

// Round 4
// 99.991 us; speedup vs baseline: 2.8074x; 1.7943x over previous
//
#include <hip/hip_runtime.h>

#define T_DIM 2048
#define B_DIM 32
#define F_DIM 1024
#define H_DIM 1024
#define PEN   -99999.0f

// d_out layout (floats)
#define SUM_OFF  0
#define DIST_OFF 32768
#define COPY_OFF 98304

// ws layout (floats)
#define WS_QPART 0              // [32][32][2048]
#define WS_QFULL 2097152        // [32][2048]
#define WS_VPART 2162688        // [16][64][1024]
#define WS_V     3211264        // [64][1024]
#define WS_CB    3276800        // [64]
#define WS_GML   3276864        // [32][4]
#define WS_PML   3276992        // [32*32][4]
#define WS_PFACC 3281088        // [32*32][1024]
#define WS_FBAR  4329664        // [32][1024]
#define WS_SPART 4362432        // [32][32][1024]

#define NCHUNK   32             // t-chunks of 64 in fused pass
#define QJT      256            // j per gemm_part block
#define GFS      32             // f-split in gemm_part
#define GFC      (F_DIM / GFS)  // 32

// part[fc][b][j] = sum_{f in chunk fc} X[b][f] * W[j][f]
// block tile: 256 j x 32 b x 32 f.  thread tile: 4j x 8b.
template<int J>
__global__ void gemm_part(const float* __restrict__ W, const float* __restrict__ X,
                          float* __restrict__ part) {
    __shared__ float swt[GFC * QJT];   // [f][jj], 16B-granule XOR swizzle
    __shared__ float sht[GFC * 32];    // [f][b],  same swizzle
    constexpr int NJ = J / QJT;
    int jt = blockIdx.x % NJ;
    int fc = blockIdx.x / NJ;
    int j0 = jt * QJT, f0 = fc * GFC;
    int tid = threadIdx.x;
    for (int idx = tid; idx < GFC * QJT; idx += 256) {
        int jj = idx >> 5, f = idx & 31;   // consecutive tid -> consecutive f (coalesced)
        swt[f * QJT + (jj ^ ((f & 7) << 2))] = W[(size_t)(j0 + jj) * F_DIM + f0 + f];
    }
    for (int idx = tid; idx < GFC * 32; idx += 256) {
        int b = idx >> 5, f = idx & 31;
        sht[f * 32 + (b ^ ((f & 7) << 2))] = X[b * F_DIM + f0 + f];
    }
    __syncthreads();
    int jg = tid & 63;          // j = j0 + jg*4 .. +3
    int bg = tid >> 6;          // b = bg*8 .. +7
    float acc[4][8];
    #pragma unroll
    for (int a = 0; a < 4; ++a)
        #pragma unroll
        for (int c = 0; c < 8; ++c) acc[a][c] = 0.f;
    #pragma unroll 8
    for (int f = 0; f < GFC; ++f) {
        int sx = (f & 7) << 2;
        float4 wv = *(float4*)&swt[f * QJT + ((jg * 4) ^ sx)];
        float4 h0 = *(float4*)&sht[f * 32 + ((bg * 8) ^ sx)];
        float4 h1 = *(float4*)&sht[f * 32 + ((bg * 8 + 4) ^ sx)];
        float w4[4] = {wv.x, wv.y, wv.z, wv.w};
        float hb[8] = {h0.x, h0.y, h0.z, h0.w, h1.x, h1.y, h1.z, h1.w};
        #pragma unroll
        for (int a = 0; a < 4; ++a)
            #pragma unroll
            for (int c = 0; c < 8; ++c)
                acc[a][c] += w4[a] * hb[c];
    }
    #pragma unroll
    for (int c = 0; c < 8; ++c) {
        float4 r = {acc[0][c], acc[1][c], acc[2][c], acc[3][c]};
        *(float4*)&part[((size_t)fc * 32 + bg * 8 + c) * J + j0 + jg * 4] = r;
    }
}

// out[b*J+j] = bias[j] + sum_{c<32} part[c][b][j]
template<int J>
__global__ void reduce32(const float* __restrict__ part, const float* __restrict__ bias,
                         float* __restrict__ out) {
    int idx = blockIdx.x * 256 + threadIdx.x;   // b*J + j
    int j = idx & (J - 1);
    float s = bias[j];
    #pragma unroll
    for (int c = 0; c < 32; ++c) s += part[(size_t)c * 32 * J + idx];
    out[idx] = s;
}

// vpart[hc][bc][f] = sum_{h in chunk} Wk[h][f] * qfull[b][2h+c],  16 f-tiles x 16 h-chunks
__global__ void vproj(const float* __restrict__ Wk, const float* __restrict__ qfull,
                      float* __restrict__ vpart) {
    __shared__ float qs[64 * 64];   // [hh][bc]
    int ft = blockIdx.x & 15;
    int hc = blockIdx.x >> 4;
    int f0 = ft * 64, h0 = hc * 64;
    int tid = threadIdx.x;
    for (int idx = tid; idx < 64 * 64; idx += 256) {
        int hh = idx >> 6, bc = idx & 63;
        qs[hh * 64 + bc] = qfull[(bc >> 1) * 2048 + 2 * (h0 + hh) + (bc & 1)];
    }
    __syncthreads();
    int f = f0 + (tid & 63);
    int bcg = tid >> 6;             // 16 bc per group
    float acc[16];
    #pragma unroll
    for (int i = 0; i < 16; ++i) acc[i] = 0.f;
    for (int hh = 0; hh < 64; ++hh) {
        float wk = Wk[(size_t)(h0 + hh) * F_DIM + f];
        const float* qrow = &qs[hh * 64 + bcg * 16];
        #pragma unroll
        for (int i = 0; i < 16; ++i) acc[i] += wk * qrow[i];
    }
    #pragma unroll
    for (int i = 0; i < 16; ++i)
        vpart[((size_t)hc * 64 + bcg * 16 + i) * F_DIM + f] = acc[i];
}

__global__ void vreduce16(const float* __restrict__ vpart, float* __restrict__ v) {
    int idx = blockIdx.x * 256 + threadIdx.x;   // 0..65535
    float s = 0.f;
    #pragma unroll
    for (int c = 0; c < 16; ++c) s += vpart[(size_t)c * 65536 + idx];
    v[idx] = s;
}

// cb[bc] = dot(bk, q[b,:,c])
__global__ void cbkern2(const float* __restrict__ bk, const float* __restrict__ qfull,
                        float* __restrict__ cb) {
    int bc = blockIdx.x;
    int b = bc >> 1, c = bc & 1;
    int tid = threadIdx.x;
    float s = 0.f;
    for (int h = tid; h < H_DIM; h += 256)
        s += bk[h] * qfull[b * 2048 + 2 * h + c];
    __shared__ float red[256];
    red[tid] = s; __syncthreads();
    for (int st = 128; st; st >>= 1) {
        if (tid < st) red[tid] += red[tid + st];
        __syncthreads();
    }
    if (tid == 0) cb[bc] = red[0];
}

// Single pass over features: raw scores -> d_out; online (m,l); weighted feature sum.
__global__ void fused_pass(const float* __restrict__ feat, const float* __restrict__ v,
                           const float* __restrict__ cb, const float* __restrict__ mask,
                           float* __restrict__ out, float* __restrict__ pml,
                           float* __restrict__ pfacc) {
    int b = blockIdx.x & 31;
    int chunk = blockIdx.x >> 5;       // 0..31
    int w = threadIdx.x >> 6;          // wave 0..3
    int lane = threadIdx.x & 63;

    float4 v0[4], v1[4];
    #pragma unroll
    for (int q = 0; q < 4; ++q) {
        v0[q] = *(const float4*)(v + (size_t)(b * 2 + 0) * F_DIM + q * 256 + lane * 4);
        v1[q] = *(const float4*)(v + (size_t)(b * 2 + 1) * F_DIM + q * 256 + lane * 4);
    }
    float c0 = cb[b * 2 + 0], c1 = cb[b * 2 + 1];

    float facc[16];
    #pragma unroll
    for (int i = 0; i < 16; ++i) facc[i] = 0.f;
    float m0 = -1e30f, l0 = 0.f, m1 = -1e30f, l1 = 0.f;

    int t0 = chunk * 64 + w * 16;
    const float* frow = feat + ((size_t)t0 * B_DIM + b) * F_DIM;
    float4 fcur[4];
    #pragma unroll
    for (int q = 0; q < 4; ++q) fcur[q] = *(const float4*)(frow + q * 256 + lane * 4);

    for (int tt = 0; tt < 16; ++tt) {
        int t = t0 + tt;
        float4 fx[4];
        #pragma unroll
        for (int q = 0; q < 4; ++q) fx[q] = fcur[q];
        if (tt < 15) {
            const float* fn = feat + ((size_t)(t + 1) * B_DIM + b) * F_DIM;
            #pragma unroll
            for (int q = 0; q < 4; ++q) fcur[q] = *(const float4*)(fn + q * 256 + lane * 4);
        }
        float a0 = 0.f, a1 = 0.f;
        #pragma unroll
        for (int q = 0; q < 4; ++q) {
            a0 += fx[q].x * v0[q].x + fx[q].y * v0[q].y + fx[q].z * v0[q].z + fx[q].w * v0[q].w;
            a1 += fx[q].x * v1[q].x + fx[q].y * v1[q].y + fx[q].z * v1[q].z + fx[q].w * v1[q].w;
        }
        for (int off = 32; off; off >>= 1) {
            a0 += __shfl_xor(a0, off, 64);
            a1 += __shfl_xor(a1, off, 64);
        }
        float mp = mask[t * B_DIM + b] * PEN;
        float s0 = a0 + c0 + mp;
        float s1 = a1 + c1 + mp;
        if (lane == 0) {
            out[DIST_OFF + t * B_DIM + b] = s0;
            out[COPY_OFF + t * B_DIM + b] = s1;
        }
        if (s0 > m0) {
            float sc = __expf(m0 - s0);
            l0 *= sc;
            #pragma unroll
            for (int i = 0; i < 16; ++i) facc[i] *= sc;
            m0 = s0;
        }
        float e0 = __expf(s0 - m0);
        l0 += e0;
        #pragma unroll
        for (int q = 0; q < 4; ++q) {
            facc[q * 4 + 0] += e0 * fx[q].x;
            facc[q * 4 + 1] += e0 * fx[q].y;
            facc[q * 4 + 2] += e0 * fx[q].z;
            facc[q * 4 + 3] += e0 * fx[q].w;
        }
        if (s1 > m1) { l1 *= __expf(m1 - s1); m1 = s1; }
        l1 += __expf(s1 - m1);
    }

    __shared__ float sfacc[4][F_DIM];   // 16 KB
    __shared__ float sml[4][4];
    #pragma unroll
    for (int q = 0; q < 4; ++q) {
        sfacc[w][q * 256 + lane * 4 + 0] = facc[q * 4 + 0];
        sfacc[w][q * 256 + lane * 4 + 1] = facc[q * 4 + 1];
        sfacc[w][q * 256 + lane * 4 + 2] = facc[q * 4 + 2];
        sfacc[w][q * 256 + lane * 4 + 3] = facc[q * 4 + 3];
    }
    if (lane == 0) {
        sml[w][0] = m0; sml[w][1] = l0; sml[w][2] = m1; sml[w][3] = l1;
    }
    __syncthreads();
    int tid = threadIdx.x;
    float M0 = fmaxf(fmaxf(sml[0][0], sml[1][0]), fmaxf(sml[2][0], sml[3][0]));
    float M1 = fmaxf(fmaxf(sml[0][2], sml[1][2]), fmaxf(sml[2][2], sml[3][2]));
    float L0 = 0.f, L1 = 0.f;
    float g[4];
    #pragma unroll
    for (int ww = 0; ww < 4; ++ww) {
        g[ww] = __expf(sml[ww][0] - M0);
        L0 += sml[ww][1] * g[ww];
        L1 += sml[ww][3] * __expf(sml[ww][2] - M1);
    }
    float4 r;
    r.x = g[0] * sfacc[0][tid * 4 + 0] + g[1] * sfacc[1][tid * 4 + 0]
        + g[2] * sfacc[2][tid * 4 + 0] + g[3] * sfacc[3][tid * 4 + 0];
    r.y = g[0] * sfacc[0][tid * 4 + 1] + g[1] * sfacc[1][tid * 4 + 1]
        + g[2] * sfacc[2][tid * 4 + 1] + g[3] * sfacc[3][tid * 4 + 1];
    r.z = g[0] * sfacc[0][tid * 4 + 2] + g[1] * sfacc[1][tid * 4 + 2]
        + g[2] * sfacc[2][tid * 4 + 2] + g[3] * sfacc[3][tid * 4 + 2];
    r.w = g[0] * sfacc[0][tid * 4 + 3] + g[1] * sfacc[1][tid * 4 + 3]
        + g[2] * sfacc[2][tid * 4 + 3] + g[3] * sfacc[3][tid * 4 + 3];
    *(float4*)(pfacc + ((size_t)(b * NCHUNK + chunk)) * F_DIM + tid * 4) = r;
    if (tid == 0) {
        float4 p = {M0, L0, M1, L1};
        *(float4*)(pml + (b * NCHUNK + chunk) * 4) = p;
    }
}

__global__ void combine_ml(const float* __restrict__ pml, float* __restrict__ gml) {
    int b = blockIdx.x;
    int lane = threadIdx.x;
    float m0 = -1e30f, l0 = 0.f, m1 = -1e30f, l1 = 0.f;
    if (lane < NCHUNK) {
        float4 p = *(const float4*)(pml + (b * NCHUNK + lane) * 4);
        m0 = p.x; l0 = p.y; m1 = p.z; l1 = p.w;
    }
    float M0 = m0, M1 = m1;
    for (int off = 32; off; off >>= 1) {
        M0 = fmaxf(M0, __shfl_xor(M0, off, 64));
        M1 = fmaxf(M1, __shfl_xor(M1, off, 64));
    }
    float e0 = l0 * __expf(m0 - M0);
    float e1 = l1 * __expf(m1 - M1);
    for (int off = 32; off; off >>= 1) {
        e0 += __shfl_xor(e0, off, 64);
        e1 += __shfl_xor(e1, off, 64);
    }
    if (lane == 0) {
        float4 p = {M0, 1.f / e0, M1, 1.f / e1};
        *(float4*)(gml + b * 4) = p;
    }
}

__global__ void dist_norm(float* __restrict__ out, const float* __restrict__ gml) {
    int idx = blockIdx.x * 256 + threadIdx.x;
    int b = idx & 31;
    float4 p = *(const float4*)(gml + b * 4);
    out[DIST_OFF + idx] = __expf(out[DIST_OFF + idx] - p.x) * p.y;
    out[COPY_OFF + idx] = __expf(out[COPY_OFF + idx] - p.z) * p.w;
}

__global__ void fbar_combine(const float* __restrict__ pfacc, const float* __restrict__ pml,
                             const float* __restrict__ gml, float* __restrict__ fbar) {
    int idx = blockIdx.x * 256 + threadIdx.x;   // 0..32767
    int b = idx >> 10;
    int f = idx & 1023;
    float M0 = gml[b * 4 + 0];
    float invL = gml[b * 4 + 1];
    float s = 0.f;
    #pragma unroll
    for (int c = 0; c < NCHUNK; ++c)
        s += __expf(pml[(b * NCHUNK + c) * 4] - M0) * pfacc[((size_t)(b * NCHUNK + c)) * F_DIM + f];
    fbar[idx] = s * invL;
}

extern "C" void kernel_launch(void* const* d_in, const int* in_sizes, int n_in,
                              void* d_out, int out_size, void* d_ws, size_t ws_size,
                              hipStream_t stream) {
    const float* feat   = (const float*)d_in[0];
    const float* hidden = (const float*)d_in[1];
    const float* mask   = (const float*)d_in[2];
    const float* Wk     = (const float*)d_in[3];
    const float* bk     = (const float*)d_in[4];
    const float* Wq     = (const float*)d_in[5];
    const float* bq     = (const float*)d_in[6];
    const float* Wm     = (const float*)d_in[7];
    const float* bm     = (const float*)d_in[8];
    float* out = (float*)d_out;
    float* ws  = (float*)d_ws;

    float* qpart = ws + WS_QPART;
    float* qfull = ws + WS_QFULL;
    float* vpart = ws + WS_VPART;
    float* v     = ws + WS_V;
    float* cb    = ws + WS_CB;
    float* gml   = ws + WS_GML;
    float* pml   = ws + WS_PML;
    float* pfacc = ws + WS_PFACC;
    float* fbar  = ws + WS_FBAR;
    float* spart = ws + WS_SPART;

    gemm_part<2048><<<GFS * (2048 / QJT), 256, 0, stream>>>(Wq, hidden, qpart);  // 256 blocks
    reduce32<2048><<<256, 256, 0, stream>>>(qpart, bq, qfull);
    vproj<<<256, 256, 0, stream>>>(Wk, qfull, vpart);
    vreduce16<<<256, 256, 0, stream>>>(vpart, v);
    cbkern2<<<64, 256, 0, stream>>>(bk, qfull, cb);
    fused_pass<<<1024, 256, 0, stream>>>(feat, v, cb, mask, out, pml, pfacc);
    combine_ml<<<32, 64, 0, stream>>>(pml, gml);
    dist_norm<<<256, 256, 0, stream>>>(out, gml);
    fbar_combine<<<128, 256, 0, stream>>>(pfacc, pml, gml, fbar);
    gemm_part<1024><<<GFS * (1024 / QJT), 256, 0, stream>>>(Wm, fbar, spart);    // 128 blocks
    reduce32<1024><<<128, 256, 0, stream>>>(spart, bm, out + SUM_OFF);
}